// Round 11
// baseline (984.328 us; speedup 1.0000x reference)
//
#include <hip/hip_runtime.h>
#include <hip/hip_bf16.h>
#include <math.h>

// ---------------------------------------------------------------------------
// GAT 2-layer forward. 6 dispatches:
//   0) memset cursor+counters
//   1) gemm_hist<128>: gemm1 (double-buffered LDS) + dst-histogram fused
//   2) scan_fused: scan_blocks -> device spin barrier -> scan_finish
//   3) scatter_z_agg: z1 (256 blks) || scatter (1792 blks) -> barrier -> agg1
//   4) gemm_hist<64>: gemm2
//   5) z_agg: z2 (all 2048 blks) -> barrier -> agg2
// Spin barriers are valid only because each fused grid is provably
// co-resident (2048 blocks x 4 waves, VGPR<=64 via __launch_bounds__(256,8),
// no LDS; scan kernel is 256 blocks). Counters re-zeroed every call by the
// memset. Global softmax max-shift skipped (logits bounded — identical).
// ---------------------------------------------------------------------------

#define NHIST 1264   // 8*158
#define NZ    256
#define NSCAT 1792   // NZ+NSCAT = 2048 = co-residency capacity

__device__ __forceinline__ unsigned f2bf(float x) {  // fp32 -> bf16 (RNE)
  unsigned u = __float_as_uint(x);
  return (u + 0x7fffu + ((u >> 16) & 1u)) >> 16;
}
__device__ __forceinline__ float bflo(unsigned p) { return __uint_as_float(p << 16); }
__device__ __forceinline__ float bfhi(unsigned p) { return __uint_as_float(p & 0xffff0000u); }

// device-scope barrier across a CO-RESIDENT grid
__device__ __forceinline__ void grid_spin_barrier(int* counter, int nblocks) {
  __syncthreads();
  if (threadIdx.x == 0) {
    __threadfence();
    __hip_atomic_fetch_add(counter, 1, __ATOMIC_ACQ_REL, __HIP_MEMORY_SCOPE_AGENT);
    while (__hip_atomic_load(counter, __ATOMIC_ACQUIRE, __HIP_MEMORY_SCOPE_AGENT) < nblocks) {
      __builtin_amdgcn_s_sleep(1);
    }
  }
  __syncthreads();
}

// Register-tiled GEMM (double-buffered LDS, 1 barrier/chunk) + fused scores;
// blocks >= ntiles run the dst-histogram (dst-partitioned %8, XCD-affine).
template <int FIN>
__global__ __launch_bounds__(256) void gemm_hist(
    const float* __restrict__ x, const float* __restrict__ W,
    const float* __restrict__ att, unsigned* __restrict__ hq,
    float* __restrict__ si, float* __restrict__ sj,
    float* __restrict__ Z, int N, int zero_z,
    const int* __restrict__ dstE, int* __restrict__ deg,
    int E, int ntiles, int step) {
  const int tid = threadIdx.x;

  if ((int)blockIdx.x >= ntiles) {
    int bid = blockIdx.x - ntiles;
    int p = bid & 7, sub = bid >> 3;
    int nsub = NHIST >> 3;
    int lo = p * step, hi = lo + step;
    int stride = nsub * 256;
    for (int e = sub * 256 + tid; e < E; e += stride) {
      int d = dstE[e];
      if (d >= lo && d < hi) atomicAdd(&deg[d], 1);
    }
    return;
  }

  __shared__ __align__(16) float xs[2][32][68];
  __shared__ __align__(16) float ws[2][32][132];
  const int NCH = FIN / 32;

  const int tc = tid & 31;
  const int tr = tid >> 5;
  const int lane = tid & 63;
  const int n0 = blockIdx.x * 64;

  if (zero_z && blockIdx.x == 0 && tid < 4) Z[tid] = 0.f;  // consumers are later dispatches

  const float4* x4 = (const float4*)x;
  const float4* W4 = (const float4*)W;

  // staging coordinates (fixed per thread)
  const int xnode0 = tid >> 3, xkq0 = tid & 7;              // r=0
  const int xnode1 = (tid + 256) >> 3, xkq1 = tid & 7;      // r=1
  const int gn0 = n0 + xnode0, gn1 = n0 + xnode1;
  int wcol[4], wkq[4];
#pragma unroll
  for (int r = 0; r < 4; ++r) { wcol[r] = (tid + r * 256) >> 3; wkq[r] = tid & 7; }

  float acc[8][4];
#pragma unroll
  for (int i = 0; i < 8; ++i)
#pragma unroll
    for (int j = 0; j < 4; ++j) acc[i][j] = 0.f;

  float4 xv0, xv1, wv[4];
  // ---- prologue: load + store chunk 0 ----
  {
    xv0 = make_float4(0.f, 0.f, 0.f, 0.f);
    xv1 = xv0;
    if (gn0 < N) xv0 = x4[(size_t)gn0 * (FIN / 4) + xkq0];
    if (gn1 < N) xv1 = x4[(size_t)gn1 * (FIN / 4) + xkq1];
#pragma unroll
    for (int r = 0; r < 4; ++r) wv[r] = W4[(size_t)wcol[r] * (FIN / 4) + wkq[r]];
    xs[0][xkq0 * 4 + 0][xnode0] = xv0.x;
    xs[0][xkq0 * 4 + 1][xnode0] = xv0.y;
    xs[0][xkq0 * 4 + 2][xnode0] = xv0.z;
    xs[0][xkq0 * 4 + 3][xnode0] = xv0.w;
    xs[0][xkq1 * 4 + 0][xnode1] = xv1.x;
    xs[0][xkq1 * 4 + 1][xnode1] = xv1.y;
    xs[0][xkq1 * 4 + 2][xnode1] = xv1.z;
    xs[0][xkq1 * 4 + 3][xnode1] = xv1.w;
#pragma unroll
    for (int r = 0; r < 4; ++r) {
      ws[0][wkq[r] * 4 + 0][wcol[r]] = wv[r].x;
      ws[0][wkq[r] * 4 + 1][wcol[r]] = wv[r].y;
      ws[0][wkq[r] * 4 + 2][wcol[r]] = wv[r].z;
      ws[0][wkq[r] * 4 + 3][wcol[r]] = wv[r].w;
    }
  }
  __syncthreads();

  for (int c = 0; c < NCH; ++c) {
    const int buf = c & 1;
    // A: issue loads for chunk c+1 (overlaps with compute below)
    if (c + 1 < NCH) {
      const int kc4 = (c + 1) * 8;
      xv0 = make_float4(0.f, 0.f, 0.f, 0.f);
      xv1 = xv0;
      if (gn0 < N) xv0 = x4[(size_t)gn0 * (FIN / 4) + kc4 + xkq0];
      if (gn1 < N) xv1 = x4[(size_t)gn1 * (FIN / 4) + kc4 + xkq1];
#pragma unroll
      for (int r = 0; r < 4; ++r) wv[r] = W4[(size_t)wcol[r] * (FIN / 4) + kc4 + wkq[r]];
    }
    // B: compute on buf
    {
      const float(*xsb)[68] = xs[buf];
      const float(*wsb)[132] = ws[buf];
#pragma unroll
      for (int k = 0; k < 32; ++k) {
        float4 wvv4 = *(const float4*)&wsb[k][tc * 4];
        float4 a0 = *(const float4*)&xsb[k][tr * 8];
        float4 a1 = *(const float4*)&xsb[k][tr * 8 + 4];
        float av[8] = {a0.x, a0.y, a0.z, a0.w, a1.x, a1.y, a1.z, a1.w};
        float wvv[4] = {wvv4.x, wvv4.y, wvv4.z, wvv4.w};
#pragma unroll
        for (int i = 0; i < 8; ++i)
#pragma unroll
          for (int j = 0; j < 4; ++j) acc[i][j] += av[i] * wvv[j];
      }
    }
    // D: store chunk c+1 into the other buffer; E: barrier
    if (c + 1 < NCH) {
      const int nb = buf ^ 1;
      xs[nb][xkq0 * 4 + 0][xnode0] = xv0.x;
      xs[nb][xkq0 * 4 + 1][xnode0] = xv0.y;
      xs[nb][xkq0 * 4 + 2][xnode0] = xv0.z;
      xs[nb][xkq0 * 4 + 3][xnode0] = xv0.w;
      xs[nb][xkq1 * 4 + 0][xnode1] = xv1.x;
      xs[nb][xkq1 * 4 + 1][xnode1] = xv1.y;
      xs[nb][xkq1 * 4 + 2][xnode1] = xv1.z;
      xs[nb][xkq1 * 4 + 3][xnode1] = xv1.w;
#pragma unroll
      for (int r = 0; r < 4; ++r) {
        ws[nb][wkq[r] * 4 + 0][wcol[r]] = wv[r].x;
        ws[nb][wkq[r] * 4 + 1][wcol[r]] = wv[r].y;
        ws[nb][wkq[r] * 4 + 2][wcol[r]] = wv[r].z;
        ws[nb][wkq[r] * 4 + 3][wcol[r]] = wv[r].w;
      }
      __syncthreads();
    }
  }

  // ------- epilogue: pack bf16x2 h + fused attention scores -------
  const int hd = tc >> 4;
  const int ch = (tc & 15) * 4;
  float ai[4], aj[4];
#pragma unroll
  for (int j = 0; j < 4; ++j) {
    ai[j] = att[hd * 128 + ch + j];
    aj[j] = att[hd * 128 + 64 + ch + j];
  }
#pragma unroll
  for (int i = 0; i < 8; ++i) {
    int node = n0 + tr * 8 + i;
    float sip = 0.f, sjp = 0.f;
    unsigned w[4];
#pragma unroll
    for (int j = 0; j < 4; ++j) {
      float v = acc[i][j];
      sip += v * ai[j];
      sjp += v * aj[j];
      float other = __shfl_xor(v, 16, 64);  // partner head, same channel
      float h0 = (tc < 16) ? v : other;
      float h1 = (tc < 16) ? other : v;
      w[j] = f2bf(h0) | (f2bf(h1) << 16);
    }
#pragma unroll
    for (int off = 8; off; off >>= 1) {
      sip += __shfl_down(sip, off, 64);
      sjp += __shfl_down(sjp, off, 64);
    }
    bool valid = node < N;
    if (valid && tc < 16) {
      *(uint4*)&hq[(size_t)node * 64 + ch] = make_uint4(w[0], w[1], w[2], w[3]);
    }
    if (valid && (lane & 15) == 0) {
      int hh = (lane >> 4) & 1;
      si[node * 2 + hh] = sip;
      sj[node * 2 + hh] = sjp;
    }
  }
}

// edge-parallel Z sum over the ORIGINAL edge list incl. self-loops
__device__ __forceinline__ void z_edge_body(
    const int* __restrict__ srcE, const int* __restrict__ dstE,
    const float2* __restrict__ si2, const float2* __restrict__ sj2,
    float* __restrict__ Zp, int E, int Etot, int tid0, int stride) {
  float z0 = 0.f, z1 = 0.f;
  for (int e = tid0; e < Etot; e += stride) {
    int s, d;
    if (e < E) { s = srcE[e]; d = dstE[e]; } else { s = d = e - E; }
    float2 siv = si2[d];
    float2 sjv = sj2[s];
    float a0 = siv.x + sjv.x;
    float a1 = siv.y + sjv.y;
    a0 = a0 >= 0.f ? a0 : 0.2f * a0;
    a1 = a1 >= 0.f ? a1 : 0.2f * a1;
    z0 += __expf(a0); z1 += __expf(a1);
  }
  __shared__ float r0[4], r1[4];
  int lane = threadIdx.x & 63, w = threadIdx.x >> 6;
#pragma unroll
  for (int off = 32; off; off >>= 1) {
    z0 += __shfl_down(z0, off, 64);
    z1 += __shfl_down(z1, off, 64);
  }
  if (lane == 0) { r0[w] = z0; r1[w] = z1; }
  __syncthreads();
  if (threadIdx.x == 0) {
    atomicAdd(&Zp[0], r0[0] + r0[1] + r0[2] + r0[3]);
    atomicAdd(&Zp[1], r1[0] + r1[1] + r1[2] + r1[3]);
  }
}

// one wave per dst node (scalarized): inline attention weights, inline
// self-loop term, acc += w * hq[src], fused head-mean + bias (+relu)
__device__ __forceinline__ void agg_body(
    const int* __restrict__ rowptr, const int* __restrict__ esrc,
    const unsigned* __restrict__ hq, const float2* __restrict__ si2,
    const float2* __restrict__ sj2, const float* __restrict__ Zp,
    const float* __restrict__ bias, float* __restrict__ out,
    int N, int do_relu, int nblocks) {
  int lane = threadIdx.x & 63;
  int wid = (blockIdx.x * 256 + threadIdx.x) >> 6;
  int nw = (nblocks * 256) >> 6;
  float z0 = 1.f / (Zp[0] + 1e-10f);
  float z1 = 1.f / (Zp[1] + 1e-10f);
  float bv = bias[lane];
  for (int n0 = wid; n0 < N; n0 += nw) {
    int n = __builtin_amdgcn_readfirstlane(n0);
    int beg = rowptr[n], end = rowptr[n + 1];
    float2 siv = si2[n];
    float acc0, acc1;
    {  // self-loop term (src = dst = n)
      float2 jv = sj2[n];
      unsigned p = hq[(size_t)n * 64 + lane];
      float a0 = siv.x + jv.x, a1 = siv.y + jv.y;
      a0 = a0 >= 0.f ? a0 : 0.2f * a0;
      a1 = a1 >= 0.f ? a1 : 0.2f * a1;
      acc0 = bflo(p) * __expf(a0);
      acc1 = bfhi(p) * __expf(a1);
    }
    int k = beg;
    for (; k + 4 <= end; k += 4) {
      int s0 = esrc[k], s1 = esrc[k + 1], s2 = esrc[k + 2], s3 = esrc[k + 3];
      float2 j0 = sj2[s0], j1 = sj2[s1], j2 = sj2[s2], j3 = sj2[s3];
      unsigned p0 = hq[(size_t)s0 * 64 + lane];
      unsigned p1 = hq[(size_t)s1 * 64 + lane];
      unsigned p2 = hq[(size_t)s2 * 64 + lane];
      unsigned p3 = hq[(size_t)s3 * 64 + lane];
      float a00 = siv.x + j0.x, a01 = siv.y + j0.y;
      float a10 = siv.x + j1.x, a11 = siv.y + j1.y;
      float a20 = siv.x + j2.x, a21 = siv.y + j2.y;
      float a30 = siv.x + j3.x, a31 = siv.y + j3.y;
      a00 = a00 >= 0.f ? a00 : 0.2f * a00;  a01 = a01 >= 0.f ? a01 : 0.2f * a01;
      a10 = a10 >= 0.f ? a10 : 0.2f * a10;  a11 = a11 >= 0.f ? a11 : 0.2f * a11;
      a20 = a20 >= 0.f ? a20 : 0.2f * a20;  a21 = a21 >= 0.f ? a21 : 0.2f * a21;
      a30 = a30 >= 0.f ? a30 : 0.2f * a30;  a31 = a31 >= 0.f ? a31 : 0.2f * a31;
      float w00 = __expf(a00), w01 = __expf(a01);
      float w10 = __expf(a10), w11 = __expf(a11);
      float w20 = __expf(a20), w21 = __expf(a21);
      float w30 = __expf(a30), w31 = __expf(a31);
      acc0 += bflo(p0) * w00 + bflo(p1) * w10 + bflo(p2) * w20 + bflo(p3) * w30;
      acc1 += bfhi(p0) * w01 + bfhi(p1) * w11 + bfhi(p2) * w21 + bfhi(p3) * w31;
    }
    for (; k < end; ++k) {
      int s = esrc[k];
      float2 jv = sj2[s];
      unsigned p = hq[(size_t)s * 64 + lane];
      float a0 = siv.x + jv.x, a1 = siv.y + jv.y;
      a0 = a0 >= 0.f ? a0 : 0.2f * a0;
      a1 = a1 >= 0.f ? a1 : 0.2f * a1;
      acc0 += bflo(p) * __expf(a0);
      acc1 += bfhi(p) * __expf(a1);
    }
    float r = 0.5f * (acc0 * z0 + acc1 * z1) + bv;
    if (do_relu) r = fmaxf(r, 0.f);
    out[(size_t)n * 64 + lane] = r;
  }
}

// scan_blocks -> grid barrier -> scan_finish (256 blocks, co-resident)
__global__ __launch_bounds__(256) void scan_fused(
    const int* __restrict__ deg, int* __restrict__ rowptr,
    int* __restrict__ bsum, int* __restrict__ cursor, int* __restrict__ counter,
    int N, int Eall, int nb) {
  __shared__ int ts[256];
  int b = blockIdx.x, t = threadIdx.x;
  if (b < nb) {
    int base = b * 1024 + t * 4;
    int v[4];
#pragma unroll
    for (int j = 0; j < 4; ++j) v[j] = (base + j < N) ? deg[base + j] : 0;
    int tot = v[0] + v[1] + v[2] + v[3];
    ts[t] = tot;
    __syncthreads();
#pragma unroll
    for (int off = 1; off < 256; off <<= 1) {
      int xx = (t >= off) ? ts[t - off] : 0;
      __syncthreads();
      ts[t] += xx;
      __syncthreads();
    }
    int run = ts[t] - tot;
#pragma unroll
    for (int j = 0; j < 4; ++j) {
      if (base + j < N) rowptr[base + j] = run;
      run += v[j];
    }
    if (t == 255) bsum[b] = ts[255];
  }
  grid_spin_barrier(counter, gridDim.x);
  // phase 2: apply block prefix (serial prefix of bsum, nb<=256, in LDS)
  if (t == 0) {
    int run = 0;
    for (int i = 0; i < nb; ++i) { ts[i] = run; run += bsum[i]; }
  }
  __syncthreads();
  int tid = blockIdx.x * 256 + t;
  int stride = gridDim.x * 256;
  for (int i = tid; i < N; i += stride) {
    int v = rowptr[i] + ts[i >> 10];
    rowptr[i] = v;
    cursor[i] = v;
  }
  if (tid == 0) rowptr[N] = Eall;
}

// z1 (blocks<NZ) || scatter (others) -> grid barrier -> agg1. 2048 blocks.
__global__ __launch_bounds__(256, 8) void scatter_z_agg(
    const int* __restrict__ srcE, const int* __restrict__ dstE,
    int* __restrict__ cursor, int* __restrict__ esrc,
    const unsigned* __restrict__ hq, const float2* __restrict__ si2,
    const float2* __restrict__ sj2, float* __restrict__ Zp,
    const float* __restrict__ bias, float* __restrict__ out,
    int* __restrict__ counter, const int* __restrict__ rowptr,
    int E, int Etot, int step, int N) {
  if ((int)blockIdx.x < NZ) {
    z_edge_body(srcE, dstE, si2, sj2, Zp, E, Etot,
                blockIdx.x * 256 + threadIdx.x, NZ * 256);
  } else {
    const int bid = blockIdx.x - NZ;
    const int p = bid & 7;
    const int sub = bid >> 3;
    const int nsub = NSCAT >> 3;
    const int lo = p * step;
    const int hi = lo + step;
    int stride = nsub * 256;
    for (int e = sub * 256 + threadIdx.x; e < E; e += stride) {
      int d = dstE[e];
      if (d >= lo && d < hi) {
        int s = srcE[e];
        int pos = atomicAdd(&cursor[d], 1);
        esrc[pos] = s;
      }
    }
  }
  grid_spin_barrier(counter, gridDim.x);
  agg_body(rowptr, esrc, hq, si2, sj2, Zp, bias, out, N, /*relu=*/1, gridDim.x);
}

// z2 (all blocks) -> grid barrier -> agg2. 2048 blocks.
__global__ __launch_bounds__(256, 8) void z_agg(
    const int* __restrict__ srcE, const int* __restrict__ dstE,
    const int* __restrict__ rowptr, const int* __restrict__ esrc,
    const unsigned* __restrict__ hq, const float2* __restrict__ si2,
    const float2* __restrict__ sj2, float* __restrict__ Zp,
    const float* __restrict__ bias, float* __restrict__ out,
    int* __restrict__ counter, int E, int Etot, int N) {
  z_edge_body(srcE, dstE, si2, sj2, Zp, E, Etot,
              blockIdx.x * 256 + threadIdx.x, gridDim.x * 256);
  grid_spin_barrier(counter, gridDim.x);
  agg_body(rowptr, esrc, hq, si2, sj2, Zp, bias, out, N, /*relu=*/0, gridDim.x);
}

extern "C" void kernel_launch(void* const* d_in, const int* in_sizes, int n_in,
                              void* d_out, int out_size, void* d_ws, size_t ws_size,
                              hipStream_t stream) {
  const float* x    = (const float*)d_in[0];
  const int*   ei   = (const int*)d_in[1];   // [2, E] int32
  const float* W1   = (const float*)d_in[2];
  const float* att1 = (const float*)d_in[3];
  const float* b1   = (const float*)d_in[4];
  const float* W2   = (const float*)d_in[5];
  const float* att2 = (const float*)d_in[6];
  const float* b2   = (const float*)d_in[7];
  float* out = (float*)d_out;

  const int N = in_sizes[0] / 128;   // 50000
  const int E = in_sizes[1] / 2;     // 800000
  const int Etot = E + N;            // incl. self-loops (Z sums only)
  const int* srcE = ei;
  const int* dstE = ei + E;

  // workspace layout (all segments 16B-aligned)
  unsigned* hq   = (unsigned*)d_ws;                 // N*64 packed bf16x2
  float* si      = (float*)(hq + (size_t)N * 64);   // N*2
  float* sj      = si + (size_t)N * 2;              // N*2
  float* Z       = sj + (size_t)N * 2;              // 4 (L1: Z[0..1], L2: Z[2..3])
  float* x2      = Z + 4;                           // N*64
  int* rowptr    = (int*)(x2 + (size_t)N * 64);     // N+1
  int* cursor    = rowptr + (N + 1);                // N (deg histogram too)
  int* counters  = cursor + N;                      // 4 spin-barrier counters
  int* esrc      = counters + 4;                    // E (real edges only)
  int* bsum      = esrc + E;                        // up to 256

  dim3 blk(256);
  int nb = (N + 1023) / 1024;
  int ntiles = (N + 63) / 64;
  int step = (N + 7) / 8;

  // zero deg/cursor + the 4 barrier counters in one memset
  hipMemsetAsync(cursor, 0, (size_t)(N + 4) * sizeof(int), stream);

  // 1) gemm1 (double-buffered) + dst-histogram fused (782+1264 co-resident)
  gemm_hist<128><<<ntiles + NHIST, blk, 0, stream>>>(
      x, W1, att1, hq, si, sj, Z, N, /*zero_z=*/1,
      dstE, cursor, E, ntiles, step);
  // 2) rowptr prefix (fused two-phase scan, 256 blocks)
  scan_fused<<<256, blk, 0, stream>>>(cursor, rowptr, bsum, cursor,
                                      counters + 0, N, E, nb);
  // 3) z1 || scatter -> barrier -> agg1 (-> x2, relu fused)
  scatter_z_agg<<<NZ + NSCAT, blk, 0, stream>>>(
      srcE, dstE, cursor, esrc, hq, (const float2*)si, (const float2*)sj,
      Z, b1, x2, counters + 1, rowptr, E, Etot, step, N);
  // 4) gemm2 (double-buffered; grid=ntiles: hist branch never taken)
  gemm_hist<64><<<ntiles, blk, 0, stream>>>(
      x2, W2, att2, hq, si, sj, Z, N, /*zero_z=*/0,
      dstE, cursor, E, ntiles, step);
  // 5) z2 (full grid) -> barrier -> agg2 (-> out)
  z_agg<<<2048, blk, 0, stream>>>(
      srcE, dstE, rowptr, esrc, hq, (const float2*)si, (const float2*)sj,
      Z + 2, b2, out, counters + 2, E, Etot, N);
}

// Round 12
// 348.128 us; speedup vs baseline: 2.8275x; 2.8275x over previous
//
#include <hip/hip_runtime.h>
#include <hip/hip_bf16.h>
#include <math.h>

// ---------------------------------------------------------------------------
// GAT 2-layer forward. Round-10 dispatch structure (separate dispatches;
// heterogeneous fusion ONLY for independent work, co-residency-aware) +
// double-buffered GEMM staging. In-kernel grid spin barriers were tried
// (round 11) and regressed 3x — dispatch boundaries are cheaper than
// device-scope barriers on this chip.
//
//   1) gemm_hist<128>: blocks[0,ntiles)=gemm1(+zero Z); +NHIST hist blocks
//   2) scan_blocks, 3) scan_finish (rowptr prefix; cursor copy)
//   4) scatter_z: z1 blocks FIRST (co-schedule), then dst-partitioned scatter
//   5) csr_aggregate -> x2 (self-loop inline; relu fused)
//   6) gemm_hist<64> grid=ntiles (pure gemm2)
//   7) z_edge -> Z[2..3]
//   8) csr_aggregate -> out
//
// CSR holds only real edges; self-loops applied inline in the aggregator.
// Global softmax max-shift skipped (logits bounded — identical result).
// ---------------------------------------------------------------------------

#define NHIST 1264   // 8*158
#define NZ    256
#define NSCAT 1792   // NZ+NSCAT = 2048 = full co-residency

__device__ __forceinline__ unsigned f2bf(float x) {  // fp32 -> bf16 (RNE)
  unsigned u = __float_as_uint(x);
  return (u + 0x7fffu + ((u >> 16) & 1u)) >> 16;
}
__device__ __forceinline__ float bflo(unsigned p) { return __uint_as_float(p << 16); }
__device__ __forceinline__ float bfhi(unsigned p) { return __uint_as_float(p & 0xffff0000u); }

// Register-tiled GEMM (double-buffered LDS, 1 barrier/chunk) + fused scores;
// blocks >= ntiles run the dst-histogram (dst-partitioned %8, XCD-affine).
template <int FIN>
__global__ __launch_bounds__(256) void gemm_hist(
    const float* __restrict__ x, const float* __restrict__ W,
    const float* __restrict__ att, unsigned* __restrict__ hq,
    float* __restrict__ si, float* __restrict__ sj,
    float* __restrict__ Z, int N, int zero_z,
    const int* __restrict__ dstE, int* __restrict__ deg,
    int E, int ntiles, int step) {
  const int tid = threadIdx.x;

  if ((int)blockIdx.x >= ntiles) {
    int bid = blockIdx.x - ntiles;
    int p = bid & 7, sub = bid >> 3;
    int nsub = NHIST >> 3;
    int lo = p * step, hi = lo + step;
    int stride = nsub * 256;
    for (int e = sub * 256 + tid; e < E; e += stride) {
      int d = dstE[e];
      if (d >= lo && d < hi) atomicAdd(&deg[d], 1);
    }
    return;
  }

  __shared__ __align__(16) float xs[2][32][68];
  __shared__ __align__(16) float ws[2][32][132];
  const int NCH = FIN / 32;

  const int tc = tid & 31;
  const int tr = tid >> 5;
  const int lane = tid & 63;
  const int n0 = blockIdx.x * 64;

  if (zero_z && blockIdx.x == 0 && tid < 4) Z[tid] = 0.f;  // consumers are later dispatches

  const float4* x4 = (const float4*)x;
  const float4* W4 = (const float4*)W;

  // staging coordinates (fixed per thread)
  const int xnode0 = tid >> 3, xkq0 = tid & 7;              // r=0
  const int xnode1 = (tid + 256) >> 3, xkq1 = tid & 7;      // r=1
  const int gn0 = n0 + xnode0, gn1 = n0 + xnode1;
  int wcol[4], wkq[4];
#pragma unroll
  for (int r = 0; r < 4; ++r) { wcol[r] = (tid + r * 256) >> 3; wkq[r] = tid & 7; }

  float acc[8][4];
#pragma unroll
  for (int i = 0; i < 8; ++i)
#pragma unroll
    for (int j = 0; j < 4; ++j) acc[i][j] = 0.f;

  float4 xv0, xv1, wv[4];
  // ---- prologue: load + store chunk 0 ----
  {
    xv0 = make_float4(0.f, 0.f, 0.f, 0.f);
    xv1 = xv0;
    if (gn0 < N) xv0 = x4[(size_t)gn0 * (FIN / 4) + xkq0];
    if (gn1 < N) xv1 = x4[(size_t)gn1 * (FIN / 4) + xkq1];
#pragma unroll
    for (int r = 0; r < 4; ++r) wv[r] = W4[(size_t)wcol[r] * (FIN / 4) + wkq[r]];
    xs[0][xkq0 * 4 + 0][xnode0] = xv0.x;
    xs[0][xkq0 * 4 + 1][xnode0] = xv0.y;
    xs[0][xkq0 * 4 + 2][xnode0] = xv0.z;
    xs[0][xkq0 * 4 + 3][xnode0] = xv0.w;
    xs[0][xkq1 * 4 + 0][xnode1] = xv1.x;
    xs[0][xkq1 * 4 + 1][xnode1] = xv1.y;
    xs[0][xkq1 * 4 + 2][xnode1] = xv1.z;
    xs[0][xkq1 * 4 + 3][xnode1] = xv1.w;
#pragma unroll
    for (int r = 0; r < 4; ++r) {
      ws[0][wkq[r] * 4 + 0][wcol[r]] = wv[r].x;
      ws[0][wkq[r] * 4 + 1][wcol[r]] = wv[r].y;
      ws[0][wkq[r] * 4 + 2][wcol[r]] = wv[r].z;
      ws[0][wkq[r] * 4 + 3][wcol[r]] = wv[r].w;
    }
  }
  __syncthreads();

  for (int c = 0; c < NCH; ++c) {
    const int buf = c & 1;
    // issue loads for chunk c+1 (overlap with compute)
    if (c + 1 < NCH) {
      const int kc4 = (c + 1) * 8;
      xv0 = make_float4(0.f, 0.f, 0.f, 0.f);
      xv1 = xv0;
      if (gn0 < N) xv0 = x4[(size_t)gn0 * (FIN / 4) + kc4 + xkq0];
      if (gn1 < N) xv1 = x4[(size_t)gn1 * (FIN / 4) + kc4 + xkq1];
#pragma unroll
      for (int r = 0; r < 4; ++r) wv[r] = W4[(size_t)wcol[r] * (FIN / 4) + kc4 + wkq[r]];
    }
    // compute on buf
    {
      const float(*xsb)[68] = xs[buf];
      const float(*wsb)[132] = ws[buf];
#pragma unroll
      for (int k = 0; k < 32; ++k) {
        float4 wvv4 = *(const float4*)&wsb[k][tc * 4];
        float4 a0 = *(const float4*)&xsb[k][tr * 8];
        float4 a1 = *(const float4*)&xsb[k][tr * 8 + 4];
        float av[8] = {a0.x, a0.y, a0.z, a0.w, a1.x, a1.y, a1.z, a1.w};
        float wvv[4] = {wvv4.x, wvv4.y, wvv4.z, wvv4.w};
#pragma unroll
        for (int i = 0; i < 8; ++i)
#pragma unroll
          for (int j = 0; j < 4; ++j) acc[i][j] += av[i] * wvv[j];
      }
    }
    // store chunk c+1 into the other buffer, single barrier
    if (c + 1 < NCH) {
      const int nb = buf ^ 1;
      xs[nb][xkq0 * 4 + 0][xnode0] = xv0.x;
      xs[nb][xkq0 * 4 + 1][xnode0] = xv0.y;
      xs[nb][xkq0 * 4 + 2][xnode0] = xv0.z;
      xs[nb][xkq0 * 4 + 3][xnode0] = xv0.w;
      xs[nb][xkq1 * 4 + 0][xnode1] = xv1.x;
      xs[nb][xkq1 * 4 + 1][xnode1] = xv1.y;
      xs[nb][xkq1 * 4 + 2][xnode1] = xv1.z;
      xs[nb][xkq1 * 4 + 3][xnode1] = xv1.w;
#pragma unroll
      for (int r = 0; r < 4; ++r) {
        ws[nb][wkq[r] * 4 + 0][wcol[r]] = wv[r].x;
        ws[nb][wkq[r] * 4 + 1][wcol[r]] = wv[r].y;
        ws[nb][wkq[r] * 4 + 2][wcol[r]] = wv[r].z;
        ws[nb][wkq[r] * 4 + 3][wcol[r]] = wv[r].w;
      }
      __syncthreads();
    }
  }

  // ------- epilogue: pack bf16x2 h + fused attention scores -------
  const int hd = tc >> 4;
  const int ch = (tc & 15) * 4;
  float ai[4], aj[4];
#pragma unroll
  for (int j = 0; j < 4; ++j) {
    ai[j] = att[hd * 128 + ch + j];
    aj[j] = att[hd * 128 + 64 + ch + j];
  }
#pragma unroll
  for (int i = 0; i < 8; ++i) {
    int node = n0 + tr * 8 + i;
    float sip = 0.f, sjp = 0.f;
    unsigned w[4];
#pragma unroll
    for (int j = 0; j < 4; ++j) {
      float v = acc[i][j];
      sip += v * ai[j];
      sjp += v * aj[j];
      float other = __shfl_xor(v, 16, 64);  // partner head, same channel
      float h0 = (tc < 16) ? v : other;
      float h1 = (tc < 16) ? other : v;
      w[j] = f2bf(h0) | (f2bf(h1) << 16);
    }
#pragma unroll
    for (int off = 8; off; off >>= 1) {
      sip += __shfl_down(sip, off, 64);
      sjp += __shfl_down(sjp, off, 64);
    }
    bool valid = node < N;
    if (valid && tc < 16) {
      *(uint4*)&hq[(size_t)node * 64 + ch] = make_uint4(w[0], w[1], w[2], w[3]);
    }
    if (valid && (lane & 15) == 0) {
      int hh = (lane >> 4) & 1;
      si[node * 2 + hh] = sip;
      sj[node * 2 + hh] = sjp;
    }
  }
}

// edge-parallel Z sum over the ORIGINAL edge list incl. self-loops
__device__ __forceinline__ void z_edge_body(
    const int* __restrict__ srcE, const int* __restrict__ dstE,
    const float2* __restrict__ si2, const float2* __restrict__ sj2,
    float* __restrict__ Zp, int E, int Etot, int tid0, int stride) {
  float z0 = 0.f, z1 = 0.f;
  for (int e = tid0; e < Etot; e += stride) {
    int s, d;
    if (e < E) { s = srcE[e]; d = dstE[e]; } else { s = d = e - E; }
    float2 siv = si2[d];
    float2 sjv = sj2[s];
    float a0 = siv.x + sjv.x;
    float a1 = siv.y + sjv.y;
    a0 = a0 >= 0.f ? a0 : 0.2f * a0;
    a1 = a1 >= 0.f ? a1 : 0.2f * a1;
    z0 += __expf(a0); z1 += __expf(a1);
  }
  __shared__ float r0[4], r1[4];
  int lane = threadIdx.x & 63, w = threadIdx.x >> 6;
#pragma unroll
  for (int off = 32; off; off >>= 1) {
    z0 += __shfl_down(z0, off, 64);
    z1 += __shfl_down(z1, off, 64);
  }
  if (lane == 0) { r0[w] = z0; r1[w] = z1; }
  __syncthreads();
  if (threadIdx.x == 0) {
    atomicAdd(&Zp[0], r0[0] + r0[1] + r0[2] + r0[3]);
    atomicAdd(&Zp[1], r1[0] + r1[1] + r1[2] + r1[3]);
  }
}

__global__ __launch_bounds__(256) void z_edge(
    const int* __restrict__ srcE, const int* __restrict__ dstE,
    const float2* __restrict__ si2, const float2* __restrict__ sj2,
    float* __restrict__ Zp, int E, int Etot) {
  z_edge_body(srcE, dstE, si2, sj2, Zp, E, Etot,
              blockIdx.x * 256 + threadIdx.x, gridDim.x * 256);
}

__global__ __launch_bounds__(256) void scan_blocks(
    const int* __restrict__ deg, int* __restrict__ rowptr,
    int* __restrict__ bsum, int N) {
  __shared__ int ts[256];
  int b = blockIdx.x, t = threadIdx.x;
  int base = b * 1024 + t * 4;
  int v[4];
#pragma unroll
  for (int j = 0; j < 4; ++j) v[j] = (base + j < N) ? deg[base + j] : 0;
  int tot = v[0] + v[1] + v[2] + v[3];
  ts[t] = tot;
  __syncthreads();
#pragma unroll
  for (int off = 1; off < 256; off <<= 1) {
    int x = (t >= off) ? ts[t - off] : 0;
    __syncthreads();
    ts[t] += x;
    __syncthreads();
  }
  int run = ts[t] - tot;
#pragma unroll
  for (int j = 0; j < 4; ++j) {
    if (base + j < N) rowptr[base + j] = run;
    run += v[j];
  }
  if (t == 255) bsum[b] = ts[255];
}

// folds the bsum scan in: serial prefix of bsum (nb<=256) in LDS per block
__global__ __launch_bounds__(256) void scan_finish(
    int* __restrict__ rowptr, const int* __restrict__ bsum,
    int* __restrict__ cursor, int N, int Eall, int nb) {
  __shared__ int pre[256];
  if (threadIdx.x == 0) {
    int run = 0;
    for (int i = 0; i < nb; ++i) { pre[i] = run; run += bsum[i]; }
  }
  __syncthreads();
  int tid = blockIdx.x * blockDim.x + threadIdx.x;
  int stride = gridDim.x * blockDim.x;
  for (int i = tid; i < N; i += stride) {
    int v = rowptr[i] + pre[i >> 10];
    rowptr[i] = v;
    cursor[i] = v;
  }
  if (tid == 0) rowptr[N] = Eall;
}

// blocks[0,NZ): z1 edge-parallel (FIRST so it co-schedules under scatter);
// blocks[NZ,NZ+NSCAT): dst-partitioned scatter (%8 XCD-affine).
__global__ __launch_bounds__(256) void scatter_z(
    const int* __restrict__ srcE, const int* __restrict__ dstE,
    int* __restrict__ cursor, int* __restrict__ esrc,
    const float2* __restrict__ si2, const float2* __restrict__ sj2,
    float* __restrict__ Zp, int E, int Etot, int step) {
  if ((int)blockIdx.x < NZ) {
    z_edge_body(srcE, dstE, si2, sj2, Zp, E, Etot,
                blockIdx.x * 256 + threadIdx.x, NZ * 256);
    return;
  }
  const int bid = blockIdx.x - NZ;
  const int p = bid & 7;
  const int sub = bid >> 3;
  const int nsub = NSCAT >> 3;
  const int lo = p * step;
  const int hi = lo + step;
  int stride = nsub * 256;
  for (int e = sub * 256 + threadIdx.x; e < E; e += stride) {
    int d = dstE[e];
    if (d >= lo && d < hi) {
      int s = srcE[e];
      int pos = atomicAdd(&cursor[d], 1);
      esrc[pos] = s;
    }
  }
}

// one wave per dst node (scalarized): inline attention weights, inline
// self-loop term, acc += w * hq[src], fused head-mean + bias (+relu)
__global__ __launch_bounds__(256) void csr_aggregate(
    const int* __restrict__ rowptr, const int* __restrict__ esrc,
    const unsigned* __restrict__ hq, const float2* __restrict__ si2,
    const float2* __restrict__ sj2, const float* __restrict__ Zp,
    const float* __restrict__ bias, float* __restrict__ out,
    int N, int do_relu) {
  int lane = threadIdx.x & 63;
  int wid = (blockIdx.x * blockDim.x + threadIdx.x) >> 6;
  int nw = (gridDim.x * blockDim.x) >> 6;
  float z0 = 1.f / (Zp[0] + 1e-10f);
  float z1 = 1.f / (Zp[1] + 1e-10f);
  float bv = bias[lane];
  for (int n0 = wid; n0 < N; n0 += nw) {
    int n = __builtin_amdgcn_readfirstlane(n0);
    int beg = rowptr[n], end = rowptr[n + 1];
    float2 siv = si2[n];
    float acc0, acc1;
    {  // self-loop term (src = dst = n)
      float2 jv = sj2[n];
      unsigned p = hq[(size_t)n * 64 + lane];
      float a0 = siv.x + jv.x, a1 = siv.y + jv.y;
      a0 = a0 >= 0.f ? a0 : 0.2f * a0;
      a1 = a1 >= 0.f ? a1 : 0.2f * a1;
      acc0 = bflo(p) * __expf(a0);
      acc1 = bfhi(p) * __expf(a1);
    }
    int k = beg;
    for (; k + 4 <= end; k += 4) {
      int s0 = esrc[k], s1 = esrc[k + 1], s2 = esrc[k + 2], s3 = esrc[k + 3];
      float2 j0 = sj2[s0], j1 = sj2[s1], j2 = sj2[s2], j3 = sj2[s3];
      unsigned p0 = hq[(size_t)s0 * 64 + lane];
      unsigned p1 = hq[(size_t)s1 * 64 + lane];
      unsigned p2 = hq[(size_t)s2 * 64 + lane];
      unsigned p3 = hq[(size_t)s3 * 64 + lane];
      float a00 = siv.x + j0.x, a01 = siv.y + j0.y;
      float a10 = siv.x + j1.x, a11 = siv.y + j1.y;
      float a20 = siv.x + j2.x, a21 = siv.y + j2.y;
      float a30 = siv.x + j3.x, a31 = siv.y + j3.y;
      a00 = a00 >= 0.f ? a00 : 0.2f * a00;  a01 = a01 >= 0.f ? a01 : 0.2f * a01;
      a10 = a10 >= 0.f ? a10 : 0.2f * a10;  a11 = a11 >= 0.f ? a11 : 0.2f * a11;
      a20 = a20 >= 0.f ? a20 : 0.2f * a20;  a21 = a21 >= 0.f ? a21 : 0.2f * a21;
      a30 = a30 >= 0.f ? a30 : 0.2f * a30;  a31 = a31 >= 0.f ? a31 : 0.2f * a31;
      float w00 = __expf(a00), w01 = __expf(a01);
      float w10 = __expf(a10), w11 = __expf(a11);
      float w20 = __expf(a20), w21 = __expf(a21);
      float w30 = __expf(a30), w31 = __expf(a31);
      acc0 += bflo(p0) * w00 + bflo(p1) * w10 + bflo(p2) * w20 + bflo(p3) * w30;
      acc1 += bfhi(p0) * w01 + bfhi(p1) * w11 + bfhi(p2) * w21 + bfhi(p3) * w31;
    }
    for (; k < end; ++k) {
      int s = esrc[k];
      float2 jv = sj2[s];
      unsigned p = hq[(size_t)s * 64 + lane];
      float a0 = siv.x + jv.x, a1 = siv.y + jv.y;
      a0 = a0 >= 0.f ? a0 : 0.2f * a0;
      a1 = a1 >= 0.f ? a1 : 0.2f * a1;
      acc0 += bflo(p) * __expf(a0);
      acc1 += bfhi(p) * __expf(a1);
    }
    float r = 0.5f * (acc0 * z0 + acc1 * z1) + bv;
    if (do_relu) r = fmaxf(r, 0.f);
    out[(size_t)n * 64 + lane] = r;
  }
}

extern "C" void kernel_launch(void* const* d_in, const int* in_sizes, int n_in,
                              void* d_out, int out_size, void* d_ws, size_t ws_size,
                              hipStream_t stream) {
  const float* x    = (const float*)d_in[0];
  const int*   ei   = (const int*)d_in[1];   // [2, E] int32
  const float* W1   = (const float*)d_in[2];
  const float* att1 = (const float*)d_in[3];
  const float* b1   = (const float*)d_in[4];
  const float* W2   = (const float*)d_in[5];
  const float* att2 = (const float*)d_in[6];
  const float* b2   = (const float*)d_in[7];
  float* out = (float*)d_out;

  const int N = in_sizes[0] / 128;   // 50000
  const int E = in_sizes[1] / 2;     // 800000
  const int Etot = E + N;            // incl. self-loops (Z sums only)
  const int* srcE = ei;
  const int* dstE = ei + E;

  // workspace layout (all segments 16B-aligned)
  unsigned* hq = (unsigned*)d_ws;                 // N*64 packed bf16x2
  float* si    = (float*)(hq + (size_t)N * 64);   // N*2
  float* sj    = si + (size_t)N * 2;              // N*2
  float* Z     = sj + (size_t)N * 2;              // 4 (L1: Z[0..1], L2: Z[2..3])
  float* x2    = Z + 4;                           // N*64
  int* rowptr  = (int*)(x2 + (size_t)N * 64);     // N+1
  int* cursor  = rowptr + (N + 1);                // N (deg histogram too)
  int* esrc    = cursor + N;                      // E (real edges only)
  int* bsum    = esrc + E;                        // up to 256

  dim3 blk(256);
  int nb = (N + 1023) / 1024;
  int ntiles = (N + 63) / 64;
  int step = (N + 7) / 8;

  hipMemsetAsync(cursor, 0, (size_t)N * sizeof(int), stream);

  // 1) gemm1 (double-buffered) + dst-histogram fused (782+1264 co-resident)
  gemm_hist<128><<<ntiles + NHIST, blk, 0, stream>>>(
      x, W1, att1, hq, si, sj, Z, N, /*zero_z=*/1,
      dstE, cursor, E, ntiles, step);
  // 2,3) rowptr prefix
  scan_blocks<<<nb, blk, 0, stream>>>(cursor, rowptr, bsum, N);
  scan_finish<<<256, blk, 0, stream>>>(rowptr, bsum, cursor, N, E, nb);
  // 4) z1 (first 256 blocks, co-scheduled) + scatter (1792 blocks)
  scatter_z<<<NZ + NSCAT, blk, 0, stream>>>(
      srcE, dstE, cursor, esrc, (const float2*)si, (const float2*)sj,
      Z, E, Etot, step);
  // 5) layer-1 aggregation -> x2 (self-loop inline; relu fused)
  csr_aggregate<<<4096, blk, 0, stream>>>(rowptr, esrc, hq, (const float2*)si,
                                          (const float2*)sj, Z, b1, x2, N, 1);
  // 6) gemm2 (double-buffered; grid=ntiles: hist branch never taken)
  gemm_hist<64><<<ntiles, blk, 0, stream>>>(
      x2, W2, att2, hq, si, sj, Z, N, /*zero_z=*/0,
      dstE, cursor, E, ntiles, step);
  // 7) z2
  z_edge<<<NZ, blk, 0, stream>>>(srcE, dstE, (const float2*)si,
                                 (const float2*)sj, Z + 2, E, Etot);
  // 8) layer-2 aggregation -> out
  csr_aggregate<<<4096, blk, 0, stream>>>(rowptr, esrc, hq, (const float2*)si,
                                          (const float2*)sj, Z + 2, b2, out, N, 0);
}